// Round 25
// baseline (117.975 us; speedup 1.0000x reference)
//
#include <hip/hip_runtime.h>
#include <math.h>

typedef unsigned short u16;
typedef unsigned int   u32;
typedef __attribute__((ext_vector_type(8)))  short          bf16x8;  // 8 bf16 (4 VGPR)
typedef __attribute__((ext_vector_type(4)))  short          bf16x4;  // 4 bf16 (2 VGPR)
typedef __attribute__((ext_vector_type(4)))  float          f32x4;
typedef __attribute__((ext_vector_type(16))) unsigned short u16x16;

// Problem dims (fixed by the reference)
static constexpr int Nn = 128;          // sequences
static constexpr int Ln = 256;          // residues
static constexpr int Dn = 256;          // model dim (= H*C)
static constexpr int ZDn = 128;         // pair dim
static constexpr int Hn = 8;            // heads
static constexpr int Cn = 32;           // head dim
static constexpr int Mrows = Nn * Ln;   // 32768 rows
static constexpr float EPS = 1e-5f;
static constexpr float LOG2E = 1.4426950408889634f;
static constexpr int HS = 32768 * 32;   // elements per head slab in [8][32768][32]
static constexpr int VTS = 268;         // V^T LDS stride (u16), conflict-free b64

// ---- bf16 helpers (raw-bit, RNE round) -----------------------------------
__device__ __forceinline__ float bf_s(u16 u)  { union { u32 i; float f; } x; x.i = ((u32)u) << 16; return x.f; }
__device__ __forceinline__ float bf_lo(u32 u) { union { u32 i; float f; } x; x.i = u << 16;         return x.f; }
__device__ __forceinline__ float bf_hi(u32 u) { union { u32 i; float f; } x; x.i = u & 0xffff0000u; return x.f; }
__device__ __forceinline__ u32 fbits(float f) { union { float f; u32 i; } x; x.f = f; return x.i; }
__device__ __forceinline__ u32 f2bf(float f) {
  const u32 i = fbits(f);
  return (i + 0x7fffu + ((i >> 16) & 1u)) >> 16;   // RNE to bf16
}
__device__ __forceinline__ u32 pk2(float a, float b) { return f2bf(a) | (f2bf(b) << 16); }
// Truncation pack (3 ops). P-weights only — lsum uses the SAME truncated P
// (ones-MFMA), so truncation noise largely cancels in the weighted average.
__device__ __forceinline__ u32 pk2_trunc(float a, float b) {
  return (fbits(b) & 0xffff0000u) | (fbits(a) >> 16);
}

// PV MFMA: 16x16x16 bf16 (K=16).
__device__ __forceinline__ f32x4 mfma16(bf16x4 a, bf16x4 b, f32x4 c) {
#if __has_builtin(__builtin_amdgcn_mfma_f32_16x16x16bf16_1k)
  return __builtin_amdgcn_mfma_f32_16x16x16bf16_1k(a, b, c, 0, 0, 0);
#else
  f32x4 d;
  asm volatile("v_mfma_f32_16x16x16_bf16 %0, %1, %2, %3"
               : "=v"(d) : "v"(a), "v"(b), "v"(c));
  return d;
#endif
}

// ---------------------------------------------------------------------------
// LayerNorm over D=256 -> bf16. One wave per row, float4 per lane. (proven)
__global__ __launch_bounds__(256) void ln_m_kernel(
    const float* __restrict__ x, const float* __restrict__ w,
    const float* __restrict__ b, u16* __restrict__ y)
{
  const int wave = threadIdx.x >> 6;
  const int lane = threadIdx.x & 63;
  const size_t row = (size_t)blockIdx.x * 4 + wave;
  const float4 xv = ((const float4*)(x + row * Dn))[lane];
  float s  = xv.x + xv.y + xv.z + xv.w;
  float s2 = xv.x*xv.x + xv.y*xv.y + xv.z*xv.z + xv.w*xv.w;
  #pragma unroll
  for (int off = 32; off; off >>= 1) {
    s  += __shfl_xor(s, off);
    s2 += __shfl_xor(s2, off);
  }
  const float mu = s * (1.0f / Dn);
  float var = s2 * (1.0f / Dn) - mu * mu;
  var = fmaxf(var, 0.0f);
  const float rstd = rsqrtf(var + EPS);
  const float4 wv = ((const float4*)w)[lane];
  const float4 bv = ((const float4*)b)[lane];
  float4 yv;
  yv.x = (xv.x - mu) * rstd * wv.x + bv.x;
  yv.y = (xv.y - mu) * rstd * wv.y + bv.y;
  yv.z = (xv.z - mu) * rstd * wv.z + bv.z;
  yv.w = (xv.w - mu) * rstd * wv.w + bv.w;
  uint2 p;
  p.x = pk2(yv.x, yv.y);
  p.y = pk2(yv.z, yv.w);
  ((uint2*)(y + row * Dn))[lane] = p;
}

// ---------------------------------------------------------------------------
// Weight convert + pair-bias fold precompute. (proven R14/R19)
__global__ __launch_bounds__(256) void wcvt_kernel(
    const float* __restrict__ wq, const float* __restrict__ wk,
    const float* __restrict__ wv, const float* __restrict__ wg,
    const float* __restrict__ wo,
    const float* __restrict__ lnz_w, const float* __restrict__ lnz_b,
    const float* __restrict__ wz,
    u16* __restrict__ wcatT, u16* __restrict__ woTh, u16* __restrict__ woTl,
    float* __restrict__ wkhT, float* __restrict__ Sv, float* __restrict__ bsv)
{
  __shared__ float lds[128][8];
  const int bid = blockIdx.x;
  const int t = threadIdx.x;            // t = k
  if (bid < 1024) {
    const int n = bid & 255, proj = bid >> 8;
    const float* W = proj == 0 ? wq : proj == 1 ? wk : proj == 2 ? wv : wg;
    float v = W[(size_t)t * 256 + n];
    if (proj == 0) v *= 0.17677669529663687f * LOG2E;   // 1/sqrt(C) * log2e
    wcatT[(size_t)bid * 256 + t] = (u16)f2bf(v);
  } else if (bid < 1280) {
    const int n = bid - 1024;
    const float x = wo[(size_t)t * 256 + n];
    const u16 h16 = (u16)f2bf(x);
    woTh[(size_t)n * 256 + t] = h16;
    woTl[(size_t)n * 256 + t] = (u16)f2bf(x - bf_s(h16));
  } else {
    if (t < 128) {
      #pragma unroll
      for (int h = 0; h < 8; ++h) {
        const float v = lnz_w[t] * wz[t * 8 + h];
        lds[t][h] = v;
        wkhT[h * 128 + t] = v;
      }
    }
    __syncthreads();
    if (t < 8) {
      float S = 0.0f, bs = 0.0f;
      for (int k = 0; k < 128; ++k) {
        S  += lds[k][t];
        bs += lnz_b[k] * wz[k * 8 + t];
      }
      Sv[t] = S; bsv[t] = LOG2E * bs;
    }
  }
}

// ---------------------------------------------------------------------------
// Pair bias via folded LN+matmul, scaled by LOG2E. (proven R14/R19)
__global__ __launch_bounds__(256) void zbias_kernel(
    const float* __restrict__ z, const float* __restrict__ wkhT,
    const float* __restrict__ Sv, const float* __restrict__ bsv,
    float* __restrict__ b2)
{
  __shared__ float zs[64][132];     // 33.8 KB (+4 pad)
  __shared__ float wkT_s[8 * 132];  // 4.2 KB, [h][k] stride 132
  __shared__ float mu_s[64], rs_s[64];
  const int t = threadIdx.x;
  const int r0 = blockIdx.x * 64;

  #pragma unroll
  for (int u = 0; u < 8; ++u) {
    const int i = u * 256 + t;
    const int row = i >> 5, c4 = i & 31;
    *(float4*)&zs[row][c4 * 4] =
        *(const float4*)(z + (size_t)(r0 + row) * 128 + c4 * 4);
  }
  #pragma unroll
  for (int u = 0; u < 4; ++u) {
    const int i = u * 256 + t;
    wkT_s[(i >> 7) * 132 + (i & 127)] = wkhT[i];
  }
  __syncthreads();

  {
    const int row = t >> 2, q = t & 3;
    float s = 0.0f, s2 = 0.0f;
    #pragma unroll
    for (int u = 0; u < 8; ++u) {
      const float4 v = *(const float4*)&zs[row][(q * 8 + u) * 4];
      s  += v.x + v.y + v.z + v.w;
      s2 += v.x*v.x + v.y*v.y + v.z*v.z + v.w*v.w;
    }
    s += __shfl_xor(s, 1); s2 += __shfl_xor(s2, 1);
    s += __shfl_xor(s, 2); s2 += __shfl_xor(s2, 2);
    if (q == 0) {
      const float mu = s * (1.0f / 128.0f);
      float var = s2 * (1.0f / 128.0f) - mu * mu;
      var = fmaxf(var, 0.0f);
      mu_s[row] = mu;
      rs_s[row] = rsqrtf(var + EPS);
    }
  }
  __syncthreads();

  {
    const int row = t >> 2, hp = t & 3;
    const int h0 = 2 * hp, h1 = 2 * hp + 1;
    float a0 = 0.0f, a1 = 0.0f;
    #pragma unroll
    for (int c4 = 0; c4 < 32; ++c4) {
      const float4 v  = *(const float4*)&zs[row][c4 * 4];
      const float4 w0 = *(const float4*)&wkT_s[h0 * 132 + c4 * 4];
      const float4 w1 = *(const float4*)&wkT_s[h1 * 132 + c4 * 4];
      a0 = fmaf(v.x, w0.x, a0); a0 = fmaf(v.y, w0.y, a0);
      a0 = fmaf(v.z, w0.z, a0); a0 = fmaf(v.w, w0.w, a0);
      a1 = fmaf(v.x, w1.x, a1); a1 = fmaf(v.y, w1.y, a1);
      a1 = fmaf(v.z, w1.z, a1); a1 = fmaf(v.w, w1.w, a1);
    }
    const float mu = mu_s[row];
    const float rs = rs_s[row] * LOG2E;   // fold log2e into the bias
    const size_t rg = (size_t)(r0 + row);
    b2[(size_t)h0 * 65536 + rg] = rs * (a0 - mu * Sv[h0]) + bsv[h0];
    b2[(size_t)h1 * 65536 + rg] = rs * (a1 - mu * Sv[h1]) + bsv[h1];
  }
}

// ---------------------------------------------------------------------------
// MFMA bf16 GEMM for qkvg — R24 2-phase pipeline + LDS-REPACK EPILOGUE:
// the old epilogue was 64 scalar 2B stores/thread (write-coalescing 8x under
// ideal). Each block writes exactly ONE proj slab (proj = blockIdx.y), so we
// repack acc -> bf16 in LDS (reusing B_s, dead after the k-loop) in two
// 64-row halves and emit 2048 cooperative uint4 stores (16 B/lane).
__global__ __launch_bounds__(512) void mfma_gemm_qkvg(
    const u16* __restrict__ A, const u16* __restrict__ BT,
    u16* __restrict__ qb, u16* __restrict__ kb,
    u16* __restrict__ vb, u16* __restrict__ gb,
    const float* __restrict__ bg)
{
  __shared__ u16 A_s[2][128 * 32];   // 2 x 8 KB
  __shared__ u16 B_s[2][256 * 32];   // 2 x 16 KB; reused as epilogue tile
  const int t  = threadIdx.x;
  const int w  = t >> 6;          // 0..7
  const int lane = t & 63;
  const int g  = lane >> 4;
  const int li = lane & 15;
  const int m0 = blockIdx.x * 128;
  const int n0 = blockIdx.y * 256;
  const int wr = (w & 1) * 64;    // 2 row-groups of 64
  const int wc = (w >> 1) * 64;   // 4 col-groups of 64

  // staging addresses (constant per thread except k0)
  const int cbA  = w * 1024 + lane * 16;
  const int rowA = cbA >> 6;
  const int kuA  = (cbA & 63) >> 1;

  const f32x4 zf = {0.f, 0.f, 0.f, 0.f};
  f32x4 acc[4][4];
  #pragma unroll
  for (int i = 0; i < 4; ++i)
    #pragma unroll
    for (int j = 0; j < 4; ++j) acc[i][j] = zf;

  // prologue: stage tile 0 into buf 0
  {
    __builtin_amdgcn_global_load_lds(
        (const __attribute__((address_space(1))) void*)
            (A + (size_t)(m0 + rowA) * 256 + 0 + kuA),
        (__attribute__((address_space(3))) void*)(A_s[0] + w * 512),
        16, 0, 0);
    #pragma unroll
    for (int i = 0; i < 2; ++i) {
      const int c   = i*8 + w;
      const int cb  = c * 1024 + lane * 16;
      const int row = cb >> 6;
      const int ku  = (cb & 63) >> 1;
      __builtin_amdgcn_global_load_lds(
          (const __attribute__((address_space(1))) void*)
              (BT + (size_t)(n0 + row) * 256 + 0 + ku),
          (__attribute__((address_space(3))) void*)(B_s[0] + c * 512),
          16, 0, 0);
    }
  }
  __syncthreads();   // tile 0 landed

  #pragma unroll
  for (int it = 0; it < 8; ++it) {
    const int cur = it & 1;
    // issue next tile's staging into the other buffer (overlaps the MFMAs)
    if (it < 7) {
      const int k0n = (it + 1) * 32;
      const int nxt = cur ^ 1;
      __builtin_amdgcn_global_load_lds(
          (const __attribute__((address_space(1))) void*)
              (A + (size_t)(m0 + rowA) * 256 + k0n + kuA),
          (__attribute__((address_space(3))) void*)(A_s[nxt] + w * 512),
          16, 0, 0);
      #pragma unroll
      for (int i = 0; i < 2; ++i) {
        const int c   = i*8 + w;
        const int cb  = c * 1024 + lane * 16;
        const int row = cb >> 6;
        const int ku  = (cb & 63) >> 1;
        __builtin_amdgcn_global_load_lds(
            (const __attribute__((address_space(1))) void*)
                (BT + (size_t)(n0 + row) * 256 + k0n + ku),
            (__attribute__((address_space(3))) void*)(B_s[nxt] + c * 512),
            16, 0, 0);
      }
    }
    // compute current tile
    bf16x8 af[4], bfr[4];
    #pragma unroll
    for (int i = 0; i < 4; ++i)
      af[i] = *(const bf16x8*)&A_s[cur][(wr + i*16 + li) * 32 + g*8];
    #pragma unroll
    for (int j = 0; j < 4; ++j)
      bfr[j] = *(const bf16x8*)&B_s[cur][(wc + j*16 + li) * 32 + g*8];
    #pragma unroll
    for (int i = 0; i < 4; ++i)
      #pragma unroll
      for (int j = 0; j < 4; ++j)
        acc[i][j] = __builtin_amdgcn_mfma_f32_16x16x32_bf16(af[i], bfr[j], acc[i][j], 0, 0, 0);
    __syncthreads();   // joins waves (done reading cur) + drains next stage
  }

  // ---- Epilogue via LDS repack (B_s dead: last k-iter issued no prefetch,
  // and its trailing barrier joined all reads). proj uniform per block.
  const int proj = blockIdx.y;
  u16* base = proj == 0 ? qb : proj == 1 ? kb : proj == 2 ? vb : gb;
  u16* E_s = &B_s[0][0];   // 16384 u16 = [64 rows][256 cols]
  #pragma unroll
  for (int half = 0; half < 2; ++half) {
    __syncthreads();   // previous half's uint4 reads done before overwrite
    if ((w & 1) == half) {   // wr == half*64: this wave owns these 64 rows
      #pragma unroll
      for (int j = 0; j < 4; ++j) {
        const int col = wc + j*16 + li;        // 0..255; bg index h*32+c == col
        const float gbias = (proj == 3) ? bg[col] : 0.0f;
        #pragma unroll
        for (int i = 0; i < 4; ++i)
          #pragma unroll
          for (int r = 0; r < 4; ++r) {
            const int row = i*16 + g*4 + r;    // 0..63
            E_s[row * 256 + col] = (u16)f2bf(acc[i][j][r] + gbias);
          }
      }
    }
    __syncthreads();
    // cooperative write-out: 2048 uint4 (512 threads x 4), 16 B/lane
    #pragma unroll
    for (int u4 = 0; u4 < 4; ++u4) {
      const int u   = u4 * 512 + t;
      const int row = u >> 5;            // 0..63
      const int c8  = (u & 31) * 8;      // 0..248, head-aligned groups
      const int hh  = c8 >> 5;
      const int cc  = c8 & 31;
      const int mrow = m0 + half*64 + row;
      *(uint4*)(base + (size_t)hh * HS + (size_t)mrow * 32 + cc) =
          *(const uint4*)&E_s[row * 256 + c8];
    }
  }
}

// ---------------------------------------------------------------------------
// MFMA attention per (h, n). (proven R23: bias-in-C, stride-268 V^T,
// K+V^T in LDS, swapped QK^T, truncation pack, ones-MFMA lsum, 8 waves)
__global__ __launch_bounds__(512) void attn_mfma_kernel(
    const u16* __restrict__ qb, const u16* __restrict__ kb,
    const u16* __restrict__ vb, const u16* __restrict__ gb,
    const float* __restrict__ b2, u16* __restrict__ obuf)
{
  __shared__ u16 VT_s[32 * VTS];      // [c][k] stride 268, 17.2 KB
  __shared__ u16 K_s[256 * 40];       // [k][c] stride 40, 20.5 KB

  const int h = blockIdx.x;
  const int n = blockIdx.y;
  const int t = threadIdx.x;
  const int w = t >> 6;
  const int lane = t & 63;
  const int g  = lane >> 4;
  const int li = lane & 15;
  const size_t hb = (size_t)h * HS;
  const size_t rowb = (size_t)n * 256;

  // ---- stage K (row-major) + V^T: 512 threads, row t>>1, 16-ch half each
  {
    const int row = t >> 1;
    const int cc  = (t & 1) * 16;
    const uint4* kg = (const uint4*)(kb + hb + (rowb + row) * 32 + cc);
    *(uint4*)&K_s[row * 40 + cc]     = kg[0];
    *(uint4*)&K_s[row * 40 + cc + 8] = kg[1];
    const u16x16 v = *(const u16x16*)(vb + hb + (rowb + row) * 32 + cc);
    #pragma unroll
    for (int c = 0; c < 16; ++c)
      VT_s[(cc + c) * VTS + row] = v[c];
  }

  // ---- Q B-frags direct from global (rows 32w+qt*16+li, 16B at g*8)
  bf16x8 qfrag[2];
  #pragma unroll
  for (int qt = 0; qt < 2; ++qt)
    qfrag[qt] = *(const bf16x8*)(qb + hb + (rowb + w*32 + qt*16 + li) * 32 + g*8);

  __syncthreads();   // K_s + VT_s visible to all waves (the ONLY barrier)

  const bf16x4 ONES = {(short)0x3F80, (short)0x3F80, (short)0x3F80, (short)0x3F80};
  const f32x4 zf = {0.f, 0.f, 0.f, 0.f};
  f32x4 oacc[2][2];
  f32x4 lacc[2];
  oacc[0][0] = zf; oacc[0][1] = zf; oacc[1][0] = zf; oacc[1][1] = zf;
  lacc[0] = zf; lacc[1] = zf;

  #pragma unroll 4
  for (int kt = 0; kt < 16; ++kt) {
    const bf16x8 kfrag = *(const bf16x8*)&K_s[(kt*16 + li) * 40 + g*8];
    const bf16x4 vf0 = *(const bf16x4*)&VT_s[(li)      * VTS + kt*16 + g*4];
    const bf16x4 vf1 = *(const bf16x4*)&VT_s[(16 + li) * VTS + kt*16 + g*4];
    #pragma unroll
    for (int qt = 0; qt < 2; ++qt) {
      const int q = w*32 + qt*16 + li;
      const f32x4 bias4 = *(const f32x4*)(b2 + ((size_t)h << 16) +
                                          (size_t)q * 256 + kt*16 + g*4);
      const f32x4 s = __builtin_amdgcn_mfma_f32_16x16x32_bf16(
          kfrag, qfrag[qt], bias4, 0, 0, 0);
      const float p0 = __builtin_amdgcn_exp2f(s[0]);
      const float p1 = __builtin_amdgcn_exp2f(s[1]);
      const float p2 = __builtin_amdgcn_exp2f(s[2]);
      const float p3 = __builtin_amdgcn_exp2f(s[3]);
      union { uint2 u; bf16x4 v; } pc;
      pc.u.x = pk2_trunc(p0, p1);
      pc.u.y = pk2_trunc(p2, p3);
      oacc[qt][0] = mfma16(vf0, pc.v, oacc[qt][0]);
      oacc[qt][1] = mfma16(vf1, pc.v, oacc[qt][1]);
      lacc[qt]    = mfma16(ONES, pc.v, lacc[qt]);
    }
  }

  float linv[2];
  linv[0] = 1.0f / lacc[0][0];
  linv[1] = 1.0f / lacc[1][0];

  // ---- sigmoid(gate) + store bf16 o (O^T frag: c = ct*16+g*4+r contiguous)
  #pragma unroll
  for (int qt = 0; qt < 2; ++qt) {
    const int q = w*32 + qt*16 + li;
    #pragma unroll
    for (int ct = 0; ct < 2; ++ct) {
      const int c0 = ct*16 + g*4;
      const uint2 gp = *(const uint2*)(gb + hb + (rowb + q) * 32 + c0);
      const float g0 = 1.0f / (1.0f + __expf(-bf_lo(gp.x)));
      const float g1 = 1.0f / (1.0f + __expf(-bf_hi(gp.x)));
      const float g2 = 1.0f / (1.0f + __expf(-bf_lo(gp.y)));
      const float g3 = 1.0f / (1.0f + __expf(-bf_hi(gp.y)));
      uint2 r;
      r.x = pk2(oacc[qt][ct][0] * linv[qt] * g0,
                oacc[qt][ct][1] * linv[qt] * g1);
      r.y = pk2(oacc[qt][ct][2] * linv[qt] * g2,
                oacc[qt][ct][3] * linv[qt] * g3);
      *(uint2*)(obuf + (rowb + q) * 256 + h*32 + c0) = r;
    }
  }
}

// ---------------------------------------------------------------------------
// Output projection — R24 2-phase pipeline form (proven).
// out (f32, d_out) = obuf (bf16) @ woT^T + bo.
__global__ __launch_bounds__(512) void out_proj_kernel(
    const u16* __restrict__ Abuf, const u16* __restrict__ woT,
    const float* __restrict__ bo, float* __restrict__ out)
{
  __shared__ u16 A_s[2][128 * 32];   // 2 x 8 KB
  __shared__ u16 B_s[2][256 * 32];   // 2 x 16 KB
  const int t  = threadIdx.x;
  const int w  = t >> 6;          // 0..7
  const int lane = t & 63;
  const int g  = lane >> 4;
  const int li = lane & 15;
  const int m0 = blockIdx.x * 128;
  const int wr = (w & 1) * 64;
  const int wc = (w >> 1) * 64;   // covers all 256 output cols

  const int cbA  = w * 1024 + lane * 16;
  const int rowA = cbA >> 6;
  const int kuA  = (cbA & 63) >> 1;

  const f32x4 zf = {0.f, 0.f, 0.f, 0.f};
  f32x4 acc[4][4];
  #pragma unroll
  for (int i = 0; i < 4; ++i)
    #pragma unroll
    for (int j = 0; j < 4; ++j) acc[i][j] = zf;

  // prologue: stage tile 0 into buf 0
  {
    __builtin_amdgcn_global_load_lds(
        (const __attribute__((address_space(1))) void*)
            (Abuf + (size_t)(m0 + rowA) * 256 + 0 + kuA),
        (__attribute__((address_space(3))) void*)(A_s[0] + w * 512),
        16, 0, 0);
    #pragma unroll
    for (int i = 0; i < 2; ++i) {
      const int c   = i*8 + w;
      const int cb  = c * 1024 + lane * 16;
      const int row = cb >> 6;
      const int ku  = (cb & 63) >> 1;
      __builtin_amdgcn_global_load_lds(
          (const __attribute__((address_space(1))) void*)
              (woT + (size_t)row * 256 + 0 + ku),
          (__attribute__((address_space(3))) void*)(B_s[0] + c * 512),
          16, 0, 0);
    }
  }
  __syncthreads();

  #pragma unroll
  for (int it = 0; it < 8; ++it) {
    const int cur = it & 1;
    if (it < 7) {
      const int k0n = (it + 1) * 32;
      const int nxt = cur ^ 1;
      __builtin_amdgcn_global_load_lds(
          (const __attribute__((address_space(1))) void*)
              (Abuf + (size_t)(m0 + rowA) * 256 + k0n + kuA),
          (__attribute__((address_space(3))) void*)(A_s[nxt] + w * 512),
          16, 0, 0);
      #pragma unroll
      for (int i = 0; i < 2; ++i) {
        const int c   = i*8 + w;
        const int cb  = c * 1024 + lane * 16;
        const int row = cb >> 6;
        const int ku  = (cb & 63) >> 1;
        __builtin_amdgcn_global_load_lds(
            (const __attribute__((address_space(1))) void*)
                (woT + (size_t)row * 256 + k0n + ku),
            (__attribute__((address_space(3))) void*)(B_s[nxt] + c * 512),
            16, 0, 0);
      }
    }
    bf16x8 af[4], bfr[4];
    #pragma unroll
    for (int i = 0; i < 4; ++i)
      af[i] = *(const bf16x8*)&A_s[cur][(wr + i*16 + li) * 32 + g*8];
    #pragma unroll
    for (int j = 0; j < 4; ++j)
      bfr[j] = *(const bf16x8*)&B_s[cur][(wc + j*16 + li) * 32 + g*8];
    #pragma unroll
    for (int i = 0; i < 4; ++i)
      #pragma unroll
      for (int j = 0; j < 4; ++j)
        acc[i][j] = __builtin_amdgcn_mfma_f32_16x16x32_bf16(af[i], bfr[j], acc[i][j], 0, 0, 0);
    __syncthreads();
  }

  // Epilogue: f32 + bias. D frag: row = g*4 + r, col = li.
  #pragma unroll
  for (int j = 0; j < 4; ++j) {
    const int col = wc + j*16 + li;
    const float bias = bo[col];
    #pragma unroll
    for (int i = 0; i < 4; ++i)
      #pragma unroll
      for (int r = 0; r < 4; ++r) {
        const int m = m0 + wr + i*16 + g*4 + r;
        out[(size_t)m * 256 + col] = acc[i][j][r] + bias;
      }
  }
}

// ---------------------------------------------------------------------------
extern "C" void kernel_launch(void* const* d_in, const int* in_sizes, int n_in,
                              void* d_out, int out_size, void* d_ws, size_t ws_size,
                              hipStream_t stream)
{
  const float* m     = (const float*)d_in[0];
  const float* z     = (const float*)d_in[1];
  const float* ln1_w = (const float*)d_in[2];
  const float* ln1_b = (const float*)d_in[3];
  const float* wq    = (const float*)d_in[4];
  const float* wk    = (const float*)d_in[5];
  const float* wv    = (const float*)d_in[6];
  const float* lnz_w = (const float*)d_in[7];
  const float* lnz_b = (const float*)d_in[8];
  const float* wz    = (const float*)d_in[9];
  const float* wg    = (const float*)d_in[10];
  const float* bg    = (const float*)d_in[11];
  const float* wo    = (const float*)d_in[12];
  const float* bo    = (const float*)d_in[13];
  float* out = (float*)d_out;

  // Workspace ~83 MiB (R8-proven envelope).
  char* ws = (char*)d_ws;
  const size_t MB = 1024 * 1024;
  u16*   mn    = (u16*)(ws);              // [32768][256] bf16; reused as obuf
  u16*   qb    = (u16*)(ws + 16*MB);      // [8][32768][32] bf16, 16 MiB
  u16*   kb    = (u16*)(ws + 32*MB);
  u16*   vb    = (u16*)(ws + 48*MB);
  u16*   gb    = (u16*)(ws + 64*MB);      // gate PRE-sigmoid (+bg)
  float* b2    = (float*)(ws + 80*MB);    // [8][256(q)][256(k)] f32 * LOG2E
  u16*   wcatT = (u16*)(ws + 82*MB);      // [1024][256] bf16, 512 KiB
  u16*   woTh  = (u16*)(ws + 82*MB + 512*1024);   // [256][256] bf16 hi
  u16*   woTl  = (u16*)(ws + 82*MB + 640*1024);   // [256][256] bf16 lo (unused)
  float* wkhT  = (float*)(ws + 82*MB + 768*1024); // [8][128] f32
  float* Sv    = (float*)(ws + 82*MB + 772*1024); // [8] f32
  float* bsv   = (float*)(ws + 82*MB + 773*1024); // [8] f32
  u16*   obuf  = mn;                      // o bf16 reuses mn slab (dead post-qkvg)

  wcvt_kernel<<<1281, 256, 0, stream>>>(wq, wk, wv, wg, wo, lnz_w, lnz_b, wz,
                                        wcatT, woTh, woTl, wkhT, Sv, bsv);
  ln_m_kernel<<<Mrows/4, 256, 0, stream>>>(m, ln1_w, ln1_b, mn);
  zbias_kernel<<<(Ln*Ln)/64, 256, 0, stream>>>(z, wkhT, Sv, bsv, b2);

  mfma_gemm_qkvg<<<dim3(Mrows/128, 1024/256), 512, 0, stream>>>(
      mn, wcatT, qb, kb, vb, gb, bg);

  attn_mfma_kernel<<<dim3(Hn, Nn), 512, 0, stream>>>(qb, kb, vb, gb, b2, obuf);

  out_proj_kernel<<<Mrows/128, 512, 0, stream>>>(obuf, woTh, bo, out);
}

// Round 26
// 113.938 us; speedup vs baseline: 1.0354x; 1.0354x over previous
//
#include <hip/hip_runtime.h>
#include <math.h>

typedef unsigned short u16;
typedef unsigned int   u32;
typedef __attribute__((ext_vector_type(8)))  short          bf16x8;  // 8 bf16 (4 VGPR)
typedef __attribute__((ext_vector_type(4)))  short          bf16x4;  // 4 bf16 (2 VGPR)
typedef __attribute__((ext_vector_type(4)))  float          f32x4;
typedef __attribute__((ext_vector_type(16))) unsigned short u16x16;

// Problem dims (fixed by the reference)
static constexpr int Nn = 128;          // sequences
static constexpr int Ln = 256;          // residues
static constexpr int Dn = 256;          // model dim (= H*C)
static constexpr int ZDn = 128;         // pair dim
static constexpr int Hn = 8;            // heads
static constexpr int Cn = 32;           // head dim
static constexpr int Mrows = Nn * Ln;   // 32768 rows
static constexpr float EPS = 1e-5f;
static constexpr float LOG2E = 1.4426950408889634f;
static constexpr int HS = 32768 * 32;   // elements per head slab in [8][32768][32]
static constexpr int VTS = 268;         // V^T LDS stride (u16), conflict-free b64

// ---- bf16 helpers (raw-bit, RNE round) -----------------------------------
__device__ __forceinline__ float bf_s(u16 u)  { union { u32 i; float f; } x; x.i = ((u32)u) << 16; return x.f; }
__device__ __forceinline__ float bf_lo(u32 u) { union { u32 i; float f; } x; x.i = u << 16;         return x.f; }
__device__ __forceinline__ float bf_hi(u32 u) { union { u32 i; float f; } x; x.i = u & 0xffff0000u; return x.f; }
__device__ __forceinline__ u32 fbits(float f) { union { float f; u32 i; } x; x.f = f; return x.i; }
__device__ __forceinline__ u32 f2bf(float f) {
  const u32 i = fbits(f);
  return (i + 0x7fffu + ((i >> 16) & 1u)) >> 16;   // RNE to bf16
}
__device__ __forceinline__ u32 pk2(float a, float b) { return f2bf(a) | (f2bf(b) << 16); }
// Truncation pack (3 ops). P-weights only — lsum uses the SAME truncated P
// (ones-MFMA), so truncation noise largely cancels in the weighted average.
__device__ __forceinline__ u32 pk2_trunc(float a, float b) {
  return (fbits(b) & 0xffff0000u) | (fbits(a) >> 16);
}

// PV MFMA: 16x16x16 bf16 (K=16).
__device__ __forceinline__ f32x4 mfma16(bf16x4 a, bf16x4 b, f32x4 c) {
#if __has_builtin(__builtin_amdgcn_mfma_f32_16x16x16bf16_1k)
  return __builtin_amdgcn_mfma_f32_16x16x16bf16_1k(a, b, c, 0, 0, 0);
#else
  f32x4 d;
  asm volatile("v_mfma_f32_16x16x16_bf16 %0, %1, %2, %3"
               : "=v"(d) : "v"(a), "v"(b), "v"(c));
  return d;
#endif
}

// ---------------------------------------------------------------------------
// LayerNorm over D=256 -> bf16. One wave per row, float4 per lane. (proven)
__global__ __launch_bounds__(256) void ln_m_kernel(
    const float* __restrict__ x, const float* __restrict__ w,
    const float* __restrict__ b, u16* __restrict__ y)
{
  const int wave = threadIdx.x >> 6;
  const int lane = threadIdx.x & 63;
  const size_t row = (size_t)blockIdx.x * 4 + wave;
  const float4 xv = ((const float4*)(x + row * Dn))[lane];
  float s  = xv.x + xv.y + xv.z + xv.w;
  float s2 = xv.x*xv.x + xv.y*xv.y + xv.z*xv.z + xv.w*xv.w;
  #pragma unroll
  for (int off = 32; off; off >>= 1) {
    s  += __shfl_xor(s, off);
    s2 += __shfl_xor(s2, off);
  }
  const float mu = s * (1.0f / Dn);
  float var = s2 * (1.0f / Dn) - mu * mu;
  var = fmaxf(var, 0.0f);
  const float rstd = rsqrtf(var + EPS);
  const float4 wv = ((const float4*)w)[lane];
  const float4 bv = ((const float4*)b)[lane];
  float4 yv;
  yv.x = (xv.x - mu) * rstd * wv.x + bv.x;
  yv.y = (xv.y - mu) * rstd * wv.y + bv.y;
  yv.z = (xv.z - mu) * rstd * wv.z + bv.z;
  yv.w = (xv.w - mu) * rstd * wv.w + bv.w;
  uint2 p;
  p.x = pk2(yv.x, yv.y);
  p.y = pk2(yv.z, yv.w);
  ((uint2*)(y + row * Dn))[lane] = p;
}

// ---------------------------------------------------------------------------
// Weight convert + pair-bias fold precompute. (proven R14/R19)
__global__ __launch_bounds__(256) void wcvt_kernel(
    const float* __restrict__ wq, const float* __restrict__ wk,
    const float* __restrict__ wv, const float* __restrict__ wg,
    const float* __restrict__ wo,
    const float* __restrict__ lnz_w, const float* __restrict__ lnz_b,
    const float* __restrict__ wz,
    u16* __restrict__ wcatT, u16* __restrict__ woTh, u16* __restrict__ woTl,
    float* __restrict__ wkhT, float* __restrict__ Sv, float* __restrict__ bsv)
{
  __shared__ float lds[128][8];
  const int bid = blockIdx.x;
  const int t = threadIdx.x;            // t = k
  if (bid < 1024) {
    const int n = bid & 255, proj = bid >> 8;
    const float* W = proj == 0 ? wq : proj == 1 ? wk : proj == 2 ? wv : wg;
    float v = W[(size_t)t * 256 + n];
    if (proj == 0) v *= 0.17677669529663687f * LOG2E;   // 1/sqrt(C) * log2e
    wcatT[(size_t)bid * 256 + t] = (u16)f2bf(v);
  } else if (bid < 1280) {
    const int n = bid - 1024;
    const float x = wo[(size_t)t * 256 + n];
    const u16 h16 = (u16)f2bf(x);
    woTh[(size_t)n * 256 + t] = h16;
    woTl[(size_t)n * 256 + t] = (u16)f2bf(x - bf_s(h16));
  } else {
    if (t < 128) {
      #pragma unroll
      for (int h = 0; h < 8; ++h) {
        const float v = lnz_w[t] * wz[t * 8 + h];
        lds[t][h] = v;
        wkhT[h * 128 + t] = v;
      }
    }
    __syncthreads();
    if (t < 8) {
      float S = 0.0f, bs = 0.0f;
      for (int k = 0; k < 128; ++k) {
        S  += lds[k][t];
        bs += lnz_b[k] * wz[k * 8 + t];
      }
      Sv[t] = S; bsv[t] = LOG2E * bs;
    }
  }
}

// ---------------------------------------------------------------------------
// Pair bias via folded LN+matmul, scaled by LOG2E. (proven R14/R19)
__global__ __launch_bounds__(256) void zbias_kernel(
    const float* __restrict__ z, const float* __restrict__ wkhT,
    const float* __restrict__ Sv, const float* __restrict__ bsv,
    float* __restrict__ b2)
{
  __shared__ float zs[64][132];     // 33.8 KB (+4 pad)
  __shared__ float wkT_s[8 * 132];  // 4.2 KB, [h][k] stride 132
  __shared__ float mu_s[64], rs_s[64];
  const int t = threadIdx.x;
  const int r0 = blockIdx.x * 64;

  #pragma unroll
  for (int u = 0; u < 8; ++u) {
    const int i = u * 256 + t;
    const int row = i >> 5, c4 = i & 31;
    *(float4*)&zs[row][c4 * 4] =
        *(const float4*)(z + (size_t)(r0 + row) * 128 + c4 * 4);
  }
  #pragma unroll
  for (int u = 0; u < 4; ++u) {
    const int i = u * 256 + t;
    wkT_s[(i >> 7) * 132 + (i & 127)] = wkhT[i];
  }
  __syncthreads();

  {
    const int row = t >> 2, q = t & 3;
    float s = 0.0f, s2 = 0.0f;
    #pragma unroll
    for (int u = 0; u < 8; ++u) {
      const float4 v = *(const float4*)&zs[row][(q * 8 + u) * 4];
      s  += v.x + v.y + v.z + v.w;
      s2 += v.x*v.x + v.y*v.y + v.z*v.z + v.w*v.w;
    }
    s += __shfl_xor(s, 1); s2 += __shfl_xor(s2, 1);
    s += __shfl_xor(s, 2); s2 += __shfl_xor(s2, 2);
    if (q == 0) {
      const float mu = s * (1.0f / 128.0f);
      float var = s2 * (1.0f / 128.0f) - mu * mu;
      var = fmaxf(var, 0.0f);
      mu_s[row] = mu;
      rs_s[row] = rsqrtf(var + EPS);
    }
  }
  __syncthreads();

  {
    const int row = t >> 2, hp = t & 3;
    const int h0 = 2 * hp, h1 = 2 * hp + 1;
    float a0 = 0.0f, a1 = 0.0f;
    #pragma unroll
    for (int c4 = 0; c4 < 32; ++c4) {
      const float4 v  = *(const float4*)&zs[row][c4 * 4];
      const float4 w0 = *(const float4*)&wkT_s[h0 * 132 + c4 * 4];
      const float4 w1 = *(const float4*)&wkT_s[h1 * 132 + c4 * 4];
      a0 = fmaf(v.x, w0.x, a0); a0 = fmaf(v.y, w0.y, a0);
      a0 = fmaf(v.z, w0.z, a0); a0 = fmaf(v.w, w0.w, a0);
      a1 = fmaf(v.x, w1.x, a1); a1 = fmaf(v.y, w1.y, a1);
      a1 = fmaf(v.z, w1.z, a1); a1 = fmaf(v.w, w1.w, a1);
    }
    const float mu = mu_s[row];
    const float rs = rs_s[row] * LOG2E;   // fold log2e into the bias
    const size_t rg = (size_t)(r0 + row);
    b2[(size_t)h0 * 65536 + rg] = rs * (a0 - mu * Sv[h0]) + bsv[h0];
    b2[(size_t)h1 * 65536 + rg] = rs * (a1 - mu * Sv[h1]) + bsv[h1];
  }
}

// ---------------------------------------------------------------------------
// MFMA bf16 GEMM for qkvg — R24 proven form: 128x256 tile, 8 waves (2M x 4N),
// 2-phase double-buffered pipeline, DIRECT-scatter epilogue (R25's LDS-repack
// epilogue regressed 4 us: pack-half serialization + extra barriers cost more
// than the coalescing win; L2 write-combining absorbs the 2B-stride stores).
__global__ __launch_bounds__(512) void mfma_gemm_qkvg(
    const u16* __restrict__ A, const u16* __restrict__ BT,
    u16* __restrict__ qb, u16* __restrict__ kb,
    u16* __restrict__ vb, u16* __restrict__ gb,
    const float* __restrict__ bg)
{
  __shared__ u16 A_s[2][128 * 32];   // 2 x 8 KB
  __shared__ u16 B_s[2][256 * 32];   // 2 x 16 KB  (48 KB total)
  const int t  = threadIdx.x;
  const int w  = t >> 6;          // 0..7
  const int lane = t & 63;
  const int g  = lane >> 4;
  const int li = lane & 15;
  const int m0 = blockIdx.x * 128;
  const int n0 = blockIdx.y * 256;
  const int wr = (w & 1) * 64;    // 2 row-groups of 64
  const int wc = (w >> 1) * 64;   // 4 col-groups of 64

  // staging addresses (constant per thread except k0)
  const int cbA  = w * 1024 + lane * 16;
  const int rowA = cbA >> 6;
  const int kuA  = (cbA & 63) >> 1;

  const f32x4 zf = {0.f, 0.f, 0.f, 0.f};
  f32x4 acc[4][4];
  #pragma unroll
  for (int i = 0; i < 4; ++i)
    #pragma unroll
    for (int j = 0; j < 4; ++j) acc[i][j] = zf;

  // prologue: stage tile 0 into buf 0
  {
    __builtin_amdgcn_global_load_lds(
        (const __attribute__((address_space(1))) void*)
            (A + (size_t)(m0 + rowA) * 256 + 0 + kuA),
        (__attribute__((address_space(3))) void*)(A_s[0] + w * 512),
        16, 0, 0);
    #pragma unroll
    for (int i = 0; i < 2; ++i) {
      const int c   = i*8 + w;
      const int cb  = c * 1024 + lane * 16;
      const int row = cb >> 6;
      const int ku  = (cb & 63) >> 1;
      __builtin_amdgcn_global_load_lds(
          (const __attribute__((address_space(1))) void*)
              (BT + (size_t)(n0 + row) * 256 + 0 + ku),
          (__attribute__((address_space(3))) void*)(B_s[0] + c * 512),
          16, 0, 0);
    }
  }
  __syncthreads();   // tile 0 landed

  #pragma unroll
  for (int it = 0; it < 8; ++it) {
    const int cur = it & 1;
    // issue next tile's staging into the other buffer (overlaps the MFMAs)
    if (it < 7) {
      const int k0n = (it + 1) * 32;
      const int nxt = cur ^ 1;
      __builtin_amdgcn_global_load_lds(
          (const __attribute__((address_space(1))) void*)
              (A + (size_t)(m0 + rowA) * 256 + k0n + kuA),
          (__attribute__((address_space(3))) void*)(A_s[nxt] + w * 512),
          16, 0, 0);
      #pragma unroll
      for (int i = 0; i < 2; ++i) {
        const int c   = i*8 + w;
        const int cb  = c * 1024 + lane * 16;
        const int row = cb >> 6;
        const int ku  = (cb & 63) >> 1;
        __builtin_amdgcn_global_load_lds(
            (const __attribute__((address_space(1))) void*)
                (BT + (size_t)(n0 + row) * 256 + k0n + ku),
            (__attribute__((address_space(3))) void*)(B_s[nxt] + c * 512),
            16, 0, 0);
      }
    }
    // compute current tile
    bf16x8 af[4], bfr[4];
    #pragma unroll
    for (int i = 0; i < 4; ++i)
      af[i] = *(const bf16x8*)&A_s[cur][(wr + i*16 + li) * 32 + g*8];
    #pragma unroll
    for (int j = 0; j < 4; ++j)
      bfr[j] = *(const bf16x8*)&B_s[cur][(wc + j*16 + li) * 32 + g*8];
    #pragma unroll
    for (int i = 0; i < 4; ++i)
      #pragma unroll
      for (int j = 0; j < 4; ++j)
        acc[i][j] = __builtin_amdgcn_mfma_f32_16x16x32_bf16(af[i], bfr[j], acc[i][j], 0, 0, 0);
    __syncthreads();   // joins waves (done reading cur) + drains next stage
  }

  // Epilogue. D frag: row = (lane>>4)*4 + r, col = lane&15
  #pragma unroll
  for (int j = 0; j < 4; ++j) {
    const int nglob = n0 + wc + j*16 + li;
    const int proj = nglob >> 8;
    const int h    = (nglob >> 5) & 7;
    const int c    = nglob & 31;
    u16* base = proj == 0 ? qb : proj == 1 ? kb : proj == 2 ? vb : gb;
    const float gbias = (proj == 3) ? bg[h*32 + c] : 0.0f;
    #pragma unroll
    for (int i = 0; i < 4; ++i)
      #pragma unroll
      for (int r = 0; r < 4; ++r) {
        const int m = m0 + wr + i*16 + g*4 + r;
        const float v = acc[i][j][r] + gbias;   // gate: PRE-sigmoid
        base[(size_t)h * HS + (size_t)m * 32 + c] = (u16)f2bf(v);
      }
  }
}

// ---------------------------------------------------------------------------
// MFMA attention per (h, n). (proven R23: bias-in-C, stride-268 V^T,
// K+V^T in LDS, swapped QK^T, truncation pack, ones-MFMA lsum, 8 waves)
__global__ __launch_bounds__(512) void attn_mfma_kernel(
    const u16* __restrict__ qb, const u16* __restrict__ kb,
    const u16* __restrict__ vb, const u16* __restrict__ gb,
    const float* __restrict__ b2, u16* __restrict__ obuf)
{
  __shared__ u16 VT_s[32 * VTS];      // [c][k] stride 268, 17.2 KB
  __shared__ u16 K_s[256 * 40];       // [k][c] stride 40, 20.5 KB

  const int h = blockIdx.x;
  const int n = blockIdx.y;
  const int t = threadIdx.x;
  const int w = t >> 6;
  const int lane = t & 63;
  const int g  = lane >> 4;
  const int li = lane & 15;
  const size_t hb = (size_t)h * HS;
  const size_t rowb = (size_t)n * 256;

  // ---- stage K (row-major) + V^T: 512 threads, row t>>1, 16-ch half each
  {
    const int row = t >> 1;
    const int cc  = (t & 1) * 16;
    const uint4* kg = (const uint4*)(kb + hb + (rowb + row) * 32 + cc);
    *(uint4*)&K_s[row * 40 + cc]     = kg[0];
    *(uint4*)&K_s[row * 40 + cc + 8] = kg[1];
    const u16x16 v = *(const u16x16*)(vb + hb + (rowb + row) * 32 + cc);
    #pragma unroll
    for (int c = 0; c < 16; ++c)
      VT_s[(cc + c) * VTS + row] = v[c];
  }

  // ---- Q B-frags direct from global (rows 32w+qt*16+li, 16B at g*8)
  bf16x8 qfrag[2];
  #pragma unroll
  for (int qt = 0; qt < 2; ++qt)
    qfrag[qt] = *(const bf16x8*)(qb + hb + (rowb + w*32 + qt*16 + li) * 32 + g*8);

  __syncthreads();   // K_s + VT_s visible to all waves (the ONLY barrier)

  const bf16x4 ONES = {(short)0x3F80, (short)0x3F80, (short)0x3F80, (short)0x3F80};
  const f32x4 zf = {0.f, 0.f, 0.f, 0.f};
  f32x4 oacc[2][2];
  f32x4 lacc[2];
  oacc[0][0] = zf; oacc[0][1] = zf; oacc[1][0] = zf; oacc[1][1] = zf;
  lacc[0] = zf; lacc[1] = zf;

  #pragma unroll 4
  for (int kt = 0; kt < 16; ++kt) {
    const bf16x8 kfrag = *(const bf16x8*)&K_s[(kt*16 + li) * 40 + g*8];
    const bf16x4 vf0 = *(const bf16x4*)&VT_s[(li)      * VTS + kt*16 + g*4];
    const bf16x4 vf1 = *(const bf16x4*)&VT_s[(16 + li) * VTS + kt*16 + g*4];
    #pragma unroll
    for (int qt = 0; qt < 2; ++qt) {
      const int q = w*32 + qt*16 + li;
      const f32x4 bias4 = *(const f32x4*)(b2 + ((size_t)h << 16) +
                                          (size_t)q * 256 + kt*16 + g*4);
      const f32x4 s = __builtin_amdgcn_mfma_f32_16x16x32_bf16(
          kfrag, qfrag[qt], bias4, 0, 0, 0);
      const float p0 = __builtin_amdgcn_exp2f(s[0]);
      const float p1 = __builtin_amdgcn_exp2f(s[1]);
      const float p2 = __builtin_amdgcn_exp2f(s[2]);
      const float p3 = __builtin_amdgcn_exp2f(s[3]);
      union { uint2 u; bf16x4 v; } pc;
      pc.u.x = pk2_trunc(p0, p1);
      pc.u.y = pk2_trunc(p2, p3);
      oacc[qt][0] = mfma16(vf0, pc.v, oacc[qt][0]);
      oacc[qt][1] = mfma16(vf1, pc.v, oacc[qt][1]);
      lacc[qt]    = mfma16(ONES, pc.v, lacc[qt]);
    }
  }

  float linv[2];
  linv[0] = 1.0f / lacc[0][0];
  linv[1] = 1.0f / lacc[1][0];

  // ---- sigmoid(gate) + store bf16 o (O^T frag: c = ct*16+g*4+r contiguous)
  #pragma unroll
  for (int qt = 0; qt < 2; ++qt) {
    const int q = w*32 + qt*16 + li;
    #pragma unroll
    for (int ct = 0; ct < 2; ++ct) {
      const int c0 = ct*16 + g*4;
      const uint2 gp = *(const uint2*)(gb + hb + (rowb + q) * 32 + c0);
      const float g0 = 1.0f / (1.0f + __expf(-bf_lo(gp.x)));
      const float g1 = 1.0f / (1.0f + __expf(-bf_hi(gp.x)));
      const float g2 = 1.0f / (1.0f + __expf(-bf_lo(gp.y)));
      const float g3 = 1.0f / (1.0f + __expf(-bf_hi(gp.y)));
      uint2 r;
      r.x = pk2(oacc[qt][ct][0] * linv[qt] * g0,
                oacc[qt][ct][1] * linv[qt] * g1);
      r.y = pk2(oacc[qt][ct][2] * linv[qt] * g2,
                oacc[qt][ct][3] * linv[qt] * g3);
      *(uint2*)(obuf + (rowb + q) * 256 + h*32 + c0) = r;
    }
  }
}

// ---------------------------------------------------------------------------
// Output projection — R24 2-phase pipeline form (proven).
// out (f32, d_out) = obuf (bf16) @ woT^T + bo.
__global__ __launch_bounds__(512) void out_proj_kernel(
    const u16* __restrict__ Abuf, const u16* __restrict__ woT,
    const float* __restrict__ bo, float* __restrict__ out)
{
  __shared__ u16 A_s[2][128 * 32];   // 2 x 8 KB
  __shared__ u16 B_s[2][256 * 32];   // 2 x 16 KB
  const int t  = threadIdx.x;
  const int w  = t >> 6;          // 0..7
  const int lane = t & 63;
  const int g  = lane >> 4;
  const int li = lane & 15;
  const int m0 = blockIdx.x * 128;
  const int wr = (w & 1) * 64;
  const int wc = (w >> 1) * 64;   // covers all 256 output cols

  const int cbA  = w * 1024 + lane * 16;
  const int rowA = cbA >> 6;
  const int kuA  = (cbA & 63) >> 1;

  const f32x4 zf = {0.f, 0.f, 0.f, 0.f};
  f32x4 acc[4][4];
  #pragma unroll
  for (int i = 0; i < 4; ++i)
    #pragma unroll
    for (int j = 0; j < 4; ++j) acc[i][j] = zf;

  // prologue: stage tile 0 into buf 0
  {
    __builtin_amdgcn_global_load_lds(
        (const __attribute__((address_space(1))) void*)
            (Abuf + (size_t)(m0 + rowA) * 256 + 0 + kuA),
        (__attribute__((address_space(3))) void*)(A_s[0] + w * 512),
        16, 0, 0);
    #pragma unroll
    for (int i = 0; i < 2; ++i) {
      const int c   = i*8 + w;
      const int cb  = c * 1024 + lane * 16;
      const int row = cb >> 6;
      const int ku  = (cb & 63) >> 1;
      __builtin_amdgcn_global_load_lds(
          (const __attribute__((address_space(1))) void*)
              (woT + (size_t)row * 256 + 0 + ku),
          (__attribute__((address_space(3))) void*)(B_s[0] + c * 512),
          16, 0, 0);
    }
  }
  __syncthreads();

  #pragma unroll
  for (int it = 0; it < 8; ++it) {
    const int cur = it & 1;
    if (it < 7) {
      const int k0n = (it + 1) * 32;
      const int nxt = cur ^ 1;
      __builtin_amdgcn_global_load_lds(
          (const __attribute__((address_space(1))) void*)
              (Abuf + (size_t)(m0 + rowA) * 256 + k0n + kuA),
          (__attribute__((address_space(3))) void*)(A_s[nxt] + w * 512),
          16, 0, 0);
      #pragma unroll
      for (int i = 0; i < 2; ++i) {
        const int c   = i*8 + w;
        const int cb  = c * 1024 + lane * 16;
        const int row = cb >> 6;
        const int ku  = (cb & 63) >> 1;
        __builtin_amdgcn_global_load_lds(
            (const __attribute__((address_space(1))) void*)
                (woT + (size_t)row * 256 + k0n + ku),
            (__attribute__((address_space(3))) void*)(B_s[nxt] + c * 512),
            16, 0, 0);
      }
    }
    bf16x8 af[4], bfr[4];
    #pragma unroll
    for (int i = 0; i < 4; ++i)
      af[i] = *(const bf16x8*)&A_s[cur][(wr + i*16 + li) * 32 + g*8];
    #pragma unroll
    for (int j = 0; j < 4; ++j)
      bfr[j] = *(const bf16x8*)&B_s[cur][(wc + j*16 + li) * 32 + g*8];
    #pragma unroll
    for (int i = 0; i < 4; ++i)
      #pragma unroll
      for (int j = 0; j < 4; ++j)
        acc[i][j] = __builtin_amdgcn_mfma_f32_16x16x32_bf16(af[i], bfr[j], acc[i][j], 0, 0, 0);
    __syncthreads();
  }

  // Epilogue: f32 + bias. D frag: row = g*4 + r, col = li.
  #pragma unroll
  for (int j = 0; j < 4; ++j) {
    const int col = wc + j*16 + li;
    const float bias = bo[col];
    #pragma unroll
    for (int i = 0; i < 4; ++i)
      #pragma unroll
      for (int r = 0; r < 4; ++r) {
        const int m = m0 + wr + i*16 + g*4 + r;
        out[(size_t)m * 256 + col] = acc[i][j][r] + bias;
      }
  }
}

// ---------------------------------------------------------------------------
extern "C" void kernel_launch(void* const* d_in, const int* in_sizes, int n_in,
                              void* d_out, int out_size, void* d_ws, size_t ws_size,
                              hipStream_t stream)
{
  const float* m     = (const float*)d_in[0];
  const float* z     = (const float*)d_in[1];
  const float* ln1_w = (const float*)d_in[2];
  const float* ln1_b = (const float*)d_in[3];
  const float* wq    = (const float*)d_in[4];
  const float* wk    = (const float*)d_in[5];
  const float* wv    = (const float*)d_in[6];
  const float* lnz_w = (const float*)d_in[7];
  const float* lnz_b = (const float*)d_in[8];
  const float* wz    = (const float*)d_in[9];
  const float* wg    = (const float*)d_in[10];
  const float* bg    = (const float*)d_in[11];
  const float* wo    = (const float*)d_in[12];
  const float* bo    = (const float*)d_in[13];
  float* out = (float*)d_out;

  // Workspace ~83 MiB (R8-proven envelope).
  char* ws = (char*)d_ws;
  const size_t MB = 1024 * 1024;
  u16*   mn    = (u16*)(ws);              // [32768][256] bf16; reused as obuf
  u16*   qb    = (u16*)(ws + 16*MB);      // [8][32768][32] bf16, 16 MiB
  u16*   kb    = (u16*)(ws + 32*MB);
  u16*   vb    = (u16*)(ws + 48*MB);
  u16*   gb    = (u16*)(ws + 64*MB);      // gate PRE-sigmoid (+bg)
  float* b2    = (float*)(ws + 80*MB);    // [8][256(q)][256(k)] f32 * LOG2E
  u16*   wcatT = (u16*)(ws + 82*MB);      // [1024][256] bf16, 512 KiB
  u16*   woTh  = (u16*)(ws + 82*MB + 512*1024);   // [256][256] bf16 hi
  u16*   woTl  = (u16*)(ws + 82*MB + 640*1024);   // [256][256] bf16 lo (unused)
  float* wkhT  = (float*)(ws + 82*MB + 768*1024); // [8][128] f32
  float* Sv    = (float*)(ws + 82*MB + 772*1024); // [8] f32
  float* bsv   = (float*)(ws + 82*MB + 773*1024); // [8] f32
  u16*   obuf  = mn;                      // o bf16 reuses mn slab (dead post-qkvg)

  wcvt_kernel<<<1281, 256, 0, stream>>>(wq, wk, wv, wg, wo, lnz_w, lnz_b, wz,
                                        wcatT, woTh, woTl, wkhT, Sv, bsv);
  ln_m_kernel<<<Mrows/4, 256, 0, stream>>>(m, ln1_w, ln1_b, mn);
  zbias_kernel<<<(Ln*Ln)/64, 256, 0, stream>>>(z, wkhT, Sv, bsv, b2);

  mfma_gemm_qkvg<<<dim3(Mrows/128, 1024/256), 512, 0, stream>>>(
      mn, wcatT, qb, kb, vb, gb, bg);

  attn_mfma_kernel<<<dim3(Hn, Nn), 512, 0, stream>>>(qb, kb, vb, gb, b2, obuf);

  out_proj_kernel<<<Mrows/128, 512, 0, stream>>>(obuf, woTh, bo, out);
}